// Round 7
// baseline (685.075 us; speedup 1.0000x reference)
//
#include <hip/hip_runtime.h>
#include <stdint.h>

#define EFFECT_DIM 758
#define ADD_DIM 10
#define EMBED_DIM 768
#define NCOLS 95000
#define NSYN 8
#define NROWS 1024
#define NT256 372            // ceil(95000/256)
#define TILE_B 32768         // bytes per (nt|mt, ks) 256x64 bf16 tile

typedef __attribute__((ext_vector_type(8))) __bf16 bf16x8;
typedef __attribute__((ext_vector_type(16))) float f32x16;
typedef __attribute__((ext_vector_type(4))) uint32_t u32x4;

// single-instruction f32 pair -> packed bf16 (RNE)
static __device__ __forceinline__ uint32_t pack2(float a, float b) {
  uint32_t r;
  asm("v_cvt_pk_bf16_f32 %0, %1, %2" : "=v"(r) : "v"(a), "v"(b));
  return r;
}

#define GLOAD16(src, dst)                                                   \
  __builtin_amdgcn_global_load_lds(                                         \
      (const __attribute__((address_space(1))) uint32_t*)(src),             \
      (__attribute__((address_space(3))) uint32_t*)(dst), 16, 0, 0)

#define F4C(f, i) ((i) == 0 ? (f).x : (i) == 1 ? (f).y : (i) == 2 ? (f).z : (f).w)

// ---------------------------------------------------------------------------
// Kernel 1: VirtualEmbedding -> bf16 A tiles.
// A tile (mtq, ks) at (mtq*12+ks)*32768: [256 rows][64 k] bf16, swizzled
// byte(r, c2) = r*128 + (c2 ^ ((r&7)<<4)).  Global row l -> tile l>>8, row l&255.
// ---------------------------------------------------------------------------
__global__ __launch_bounds__(256) void emb_kernel(
    const int* __restrict__ ids, const float* __restrict__ W_emb,
    const float* __restrict__ padding, const int* __restrict__ syn_table,
    const int* __restrict__ syn_mask, char* __restrict__ ws)
{
  const int l = blockIdx.x;
  const int t = threadIdx.x;
  const int id = ids[l];
  int sid[NSYN];
  int msk[NSYN];
#pragma unroll
  for (int k = 0; k < NSYN; ++k) {
    sid[k] = syn_table[id * NSYN + k];
    msk[k] = syn_mask[id * NSYN + k];
  }

  double p[9] = {0, 0, 0, 0, 0, 0, 0, 0, 0};
  for (int d = t; d < EFFECT_DIM; d += 256) {
    p[0] += (double)W_emb[(size_t)id * EFFECT_DIM + d];
#pragma unroll
    for (int k = 0; k < NSYN; ++k)
      p[k + 1] += (double)W_emb[(size_t)sid[k] * EFFECT_DIM + d];
  }

  __shared__ double s_red[9][4];
  const int w = t >> 6;
#pragma unroll
  for (int k = 0; k < 9; ++k) {
    double v = p[k];
#pragma unroll
    for (int off = 32; off > 0; off >>= 1) v += __shfl_down(v, off, 64);
    if ((t & 63) == 0) s_red[k][w] = v;
  }
  __syncthreads();

  const double isum = s_red[0][0] + s_red[0][1] + s_red[0][2] + s_red[0][3];
  float coef[NSYN];
#pragma unroll
  for (int k = 0; k < NSYN; ++k) {
    double ss = s_red[k + 1][0] + s_red[k + 1][1] + s_red[k + 1][2] + s_red[k + 1][3];
    coef[k] = msk[k] ? (float)(isum / ss) : 0.0f;
  }

  const int r  = l & 255;
  const int sw = (r & 7) << 4;
  char* wbase = ws + (size_t)(l >> 8) * (12 * TILE_B);

  for (int j = t; j < 384; j += 256) {
    const int d0 = 2 * j;
    float v0, v1;
    if (d0 < EFFECT_DIM) {
      const float* bp = W_emb + (size_t)id * EFFECT_DIM + d0;
      v0 = bp[0];
      v1 = bp[1];
#pragma unroll
      for (int k = 0; k < NSYN; ++k) {
        const float* sp = W_emb + (size_t)sid[k] * EFFECT_DIM + d0;
        v0 = fmaf(coef[k], sp[0], v0);
        v1 = fmaf(coef[k], sp[1], v1);
      }
    } else {
      v0 = padding[l * ADD_DIM + (d0 - EFFECT_DIM)];
      v1 = padding[l * ADD_DIM + (d0 + 1 - EFFECT_DIM)];
    }
    const int ks = j >> 5;
    const int jl = j & 31;
    *(uint32_t*)(wbase + ks * TILE_B + r * 128 + ((jl * 4) ^ sw)) = pack2(v0, v1);
  }
}

// ---------------------------------------------------------------------------
// Kernel 1b: W_rev f32 -> bf16 [n][k] swizzled 256-row tiles.
// Block (j, ks): covers global n [j*128, j*128+128); writes half (j&1) of
// tile (nt=j>>1, ks) at (nt*12+ks)*32768 + (j&1)*16384. float4 loads.
// ---------------------------------------------------------------------------
__global__ __launch_bounds__(256) void conv_kernel(
    const float* __restrict__ Wrev, char* __restrict__ Bbuf)
{
  __shared__ char lds[16384];
  const int t   = threadIdx.x;
  const int j   = blockIdx.x;
  const int ks  = blockIdx.y;
  const int nl4 = t & 31;
  const int kc  = t >> 5;
  const int gn4 = j * 128 + nl4 * 4;
  const bool valid = (gn4 + 4) <= NCOLS;

  float4 v[8];
  const float* p = Wrev + (size_t)(ks * 64 + kc * 8) * NCOLS + gn4;
#pragma unroll
  for (int jj = 0; jj < 8; ++jj)
    v[jj] = valid ? *(const float4*)(p + (size_t)jj * NCOLS)
                  : float4{0.0f, 0.0f, 0.0f, 0.0f};

#pragma unroll
  for (int i = 0; i < 4; ++i) {
    const int n = nl4 * 4 + i;   // local row within this 128-half
    u32x4 u;
#pragma unroll
    for (int j2 = 0; j2 < 4; ++j2)
      u[j2] = pack2(F4C(v[2 * j2], i), F4C(v[2 * j2 + 1], i));
    *(u32x4*)(lds + n * 128 + ((kc * 16) ^ ((n & 7) << 4))) = u;
  }
  __syncthreads();

  char* dst = Bbuf + (size_t)((j >> 1) * 12 + ks) * TILE_B + (j & 1) * 16384;
#pragma unroll
  for (int i = 0; i < 4; ++i)
    *(u32x4*)(dst + t * 16 + i * 4096) = *(const u32x4*)(lds + t * 16 + i * 4096);
}

// ---------------------------------------------------------------------------
// Kernel 2 (v4): 256x256 block tile, 512 threads, 8 waves (2m x 4n),
// wave-tile 128x64 (4x2 of 32x32 frags) -> read/MFMA 0.75, 32 MFMA/wave per
// barrier pair. 64KB single-buffer LDS (A 32K + B 32K), sync 2-barrier loop.
// T1 XCD remap: 1488 = 8 x 186; 4 m-blocks sharing a B panel co-resident.
// ---------------------------------------------------------------------------
__global__ __launch_bounds__(512, 2) void gemm_pre(
    const char* __restrict__ Abuf, const char* __restrict__ Bbuf,
    float* __restrict__ out)
{
  __shared__ char lds[65536];  // A: [0,32K), B: [32K,64K)
  const int t  = threadIdx.x;
  const int l  = t & 63;
  const int w  = t >> 6;   // 0..7
  const int wm = w >> 2;   // 0..1 (m half)
  const int wn = w & 3;    // 0..3 (n quarter)
  const int lr = l & 31;
  const int lh = l >> 5;

  const int wgid = blockIdx.x;
  const int xcd  = wgid & 7;
  const int work = xcd * 186 + (wgid >> 3);
  const int mt = work & 3;          // 4 m-tiles of 256 rows
  const int nt = work >> 2;         // 372 n-tiles of 256 cols
  const int n0 = nt * 256;

  f32x16 acc[4][2] = {};

  const char* asrc = Abuf + (size_t)mt * (12 * TILE_B);
  const char* bsrc = Bbuf + (size_t)nt * (12 * TILE_B);

  const int ra0 = wm * 128 + lr;          // + mr*32
  const int rb0 = wn * 64 + lr;           // + nr*32

  for (int ks = 0; ks < 12; ++ks) {
    // stage 64KB: 8 x gload16 per thread (A 4, B 4), linear pre-swizzled src
    {
      const char* sa = asrc + ks * TILE_B + t * 16;
      const char* sb = bsrc + ks * TILE_B + t * 16;
      char* da = lds + w * 1024;           // + lane*16 by HW
      char* db = lds + 32768 + w * 1024;
#pragma unroll
      for (int i = 0; i < 4; ++i) {
        GLOAD16(sa + i * 8192, da + i * 8192);
        GLOAD16(sb + i * 8192, db + i * 8192);
      }
    }
    __syncthreads();

#pragma unroll
    for (int kk = 0; kk < 4; ++kk) {
      const int c2 = kk * 32 + lh * 16;
      bf16x8 a[4], b[2];
#pragma unroll
      for (int mr = 0; mr < 4; ++mr) {
        const int r = ra0 + mr * 32;
        a[mr] = *(const bf16x8*)(lds + r * 128 + (c2 ^ ((r & 7) << 4)));
      }
#pragma unroll
      for (int nr = 0; nr < 2; ++nr) {
        const int r = rb0 + nr * 32;
        b[nr] = *(const bf16x8*)(lds + 32768 + r * 128 + (c2 ^ ((r & 7) << 4)));
      }
      __builtin_amdgcn_s_setprio(1);
#pragma unroll
      for (int mr = 0; mr < 4; ++mr)
#pragma unroll
        for (int nr = 0; nr < 2; ++nr)
          acc[mr][nr] = __builtin_amdgcn_mfma_f32_32x32x16_bf16(
              a[mr], b[nr], acc[mr][nr], 0, 0, 0);
      __builtin_amdgcn_s_setprio(0);
    }
    __syncthreads();
  }

  // epilogue: C layout col=lane&31, row=(reg&3)+8*(reg>>2)+4*(lane>>5)
#pragma unroll
  for (int nr = 0; nr < 2; ++nr) {
    const int gc = n0 + wn * 64 + nr * 32 + lr;
    if (gc < NCOLS) {
#pragma unroll
      for (int mr = 0; mr < 4; ++mr)
#pragma unroll
        for (int reg = 0; reg < 16; ++reg) {
          const int row = (reg & 3) + 8 * (reg >> 2) + 4 * lh;
          const int gr = mt * 256 + wm * 128 + mr * 32 + row;
          out[(size_t)gr * NCOLS + gc] = acc[mr][nr][reg];
        }
    }
  }
}

// ---------------------------------------------------------------------------
// Fallback GEMM (ws too small for Bbuf): 128^2 tile, inline convert.
// A addressing adapted to the 256-row tile layout.
// ---------------------------------------------------------------------------
__global__ __launch_bounds__(256, 2) void gemm_kernel(
    const float* __restrict__ Wrev, const char* __restrict__ Abuf,
    float* __restrict__ out)
{
  __shared__ char lds[32768];
  const int t  = threadIdx.x;
  const int l  = t & 63;
  const int w  = t >> 6;
  const int wm = w >> 1;
  const int wn = w & 1;
  const int lr = l & 31;
  const int lh = l >> 5;
  const int mt = blockIdx.x;
  const int n0 = blockIdx.y * 128;

  f32x16 acc[2][2] = {};

  const char* asrc = Abuf + (size_t)(mt >> 1) * (12 * TILE_B) + (mt & 1) * 16384;
  const int nl = t & 127;
  const int kc_base = t >> 7;
  const int gn = n0 + nl;
  const int bswz = (nl & 7) << 4;

  for (int ks = 0; ks < 12; ++ks) {
    {
      const char* s = asrc + ks * TILE_B + w * 1024 + l * 16;
      char* d = lds + w * 1024;
#pragma unroll
      for (int i = 0; i < 4; ++i)
        GLOAD16(s + i * 4096, d + i * 4096);
    }
#pragma unroll
    for (int task = 0; task < 4; ++task) {
      const int kc = kc_base + task * 2;
      float v[8];
      const float* p = Wrev + (size_t)(ks * 64 + kc * 8) * NCOLS + gn;
#pragma unroll
      for (int j = 0; j < 8; ++j)
        v[j] = (gn < NCOLS) ? p[(size_t)j * NCOLS] : 0.0f;
      u32x4 u;
#pragma unroll
      for (int j = 0; j < 4; ++j)
        u[j] = pack2(v[2 * j], v[2 * j + 1]);
      *(u32x4*)(lds + 16384 + nl * 128 + ((kc * 16) ^ bswz)) = u;
    }
    __syncthreads();

    bf16x8 af[2][4], bg[2][4];
#pragma unroll
    for (int mr = 0; mr < 2; ++mr) {
      const int rr = wm * 64 + mr * 32 + lr;
      const int swz = (rr & 7) << 4;
#pragma unroll
      for (int kk = 0; kk < 4; ++kk) {
        const int c2 = kk * 32 + lh * 16;
        af[mr][kk] = *(const bf16x8*)(lds + rr * 128 + (c2 ^ swz));
      }
    }
#pragma unroll
    for (int nr = 0; nr < 2; ++nr) {
      const int rr = wn * 64 + nr * 32 + lr;
      const int swz = (rr & 7) << 4;
#pragma unroll
      for (int kk = 0; kk < 4; ++kk) {
        const int c2 = kk * 32 + lh * 16;
        bg[nr][kk] = *(const bf16x8*)(lds + 16384 + rr * 128 + (c2 ^ swz));
      }
    }
#pragma unroll
    for (int kk = 0; kk < 4; ++kk)
#pragma unroll
      for (int mr = 0; mr < 2; ++mr)
#pragma unroll
        for (int nr = 0; nr < 2; ++nr)
          acc[mr][nr] = __builtin_amdgcn_mfma_f32_32x32x16_bf16(
              af[mr][kk], bg[nr][kk], acc[mr][nr], 0, 0, 0);
    __syncthreads();
  }

#pragma unroll
  for (int mr = 0; mr < 2; ++mr)
#pragma unroll
    for (int nr = 0; nr < 2; ++nr) {
      const int gc = n0 + wn * 64 + nr * 32 + lr;
      if (gc < NCOLS) {
#pragma unroll
        for (int reg = 0; reg < 16; ++reg) {
          const int row = (reg & 3) + 8 * (reg >> 2) + 4 * lh;
          const int gr = mt * 128 + wm * 64 + mr * 32 + row;
          out[(size_t)gr * NCOLS + gc] = acc[mr][nr][reg];
        }
      }
    }
}

extern "C" void kernel_launch(void* const* d_in, const int* in_sizes, int n_in,
                              void* d_out, int out_size, void* d_ws, size_t ws_size,
                              hipStream_t stream) {
  const int*   ids       = (const int*)d_in[0];
  const float* W_emb     = (const float*)d_in[1];
  const float* W_rev     = (const float*)d_in[2];
  const float* padding   = (const float*)d_in[3];
  const int*   syn_table = (const int*)d_in[4];
  const int*   syn_mask  = (const int*)d_in[5];
  float* out = (float*)d_out;
  char*  ws  = (char*)d_ws;

  const size_t A_BYTES = (size_t)4 * 12 * TILE_B;        // 1.5 MB
  const size_t B_BYTES = (size_t)NT256 * 12 * TILE_B;    // ~146 MB

  hipLaunchKernelGGL(emb_kernel, dim3(NROWS), dim3(256), 0, stream,
                     ids, W_emb, padding, syn_table, syn_mask, ws);

  if (ws_size >= A_BYTES + B_BYTES) {
    char* Bbuf = ws + A_BYTES;
    hipLaunchKernelGGL(conv_kernel, dim3(NT256 * 2, 12), dim3(256), 0, stream,
                       W_rev, Bbuf);
    hipLaunchKernelGGL(gemm_pre, dim3(4 * NT256 * 2), dim3(512), 0, stream,
                       ws, Bbuf, out);
  } else {
    hipLaunchKernelGGL(gemm_kernel, dim3(8, (NCOLS + 127) / 128), dim3(256), 0,
                       stream, W_rev, ws, out);
  }
}

// Round 8
// 373.347 us; speedup vs baseline: 1.8350x; 1.8350x over previous
//
#include <hip/hip_runtime.h>
#include <stdint.h>

#define EFFECT_DIM 758
#define ADD_DIM 10
#define EMBED_DIM 768
#define NCOLS 95000
#define NSYN 8
#define NROWS 1024
#define NT256 372            // ceil(95000/256)
#define TILE_B 32768         // bytes per 256x64 bf16 tile: [k0 16K][k1 16K] units

typedef __attribute__((ext_vector_type(8))) __bf16 bf16x8;
typedef __attribute__((ext_vector_type(16))) float f32x16;
typedef __attribute__((ext_vector_type(4))) uint32_t u32x4;

// single-instruction f32 pair -> packed bf16 (RNE)
static __device__ __forceinline__ uint32_t pack2(float a, float b) {
  uint32_t r;
  asm("v_cvt_pk_bf16_f32 %0, %1, %2" : "=v"(r) : "v"(a), "v"(b));
  return r;
}

#define GLOAD16(src, dst)                                                   \
  __builtin_amdgcn_global_load_lds(                                         \
      (const __attribute__((address_space(1))) uint32_t*)(src),             \
      (__attribute__((address_space(3))) uint32_t*)(dst), 16, 0, 0)

#define F4C(f, i) ((i) == 0 ? (f).x : (i) == 1 ? (f).y : (i) == 2 ? (f).z : (f).w)

// Unit layout (everywhere): a 256x64 bf16 tile = 2 k-half units of 16KB.
// Unit kappa holds k-bytes [kappa*64, kappa*64+64) of each row, row stride 64B,
// swizzled: byte(r, c) = r*64 + (c ^ ((r&3)<<4)).

// ---------------------------------------------------------------------------
// Kernel 1: VirtualEmbedding -> bf16 A tiles (4 m-tiles x 12 ks).
// A tile (mtq, ks) at (mtq*12+ks)*32768.
// ---------------------------------------------------------------------------
__global__ __launch_bounds__(256) void emb_kernel(
    const int* __restrict__ ids, const float* __restrict__ W_emb,
    const float* __restrict__ padding, const int* __restrict__ syn_table,
    const int* __restrict__ syn_mask, char* __restrict__ ws)
{
  const int l = blockIdx.x;
  const int t = threadIdx.x;
  const int id = ids[l];
  int sid[NSYN];
  int msk[NSYN];
#pragma unroll
  for (int k = 0; k < NSYN; ++k) {
    sid[k] = syn_table[id * NSYN + k];
    msk[k] = syn_mask[id * NSYN + k];
  }

  double p[9] = {0, 0, 0, 0, 0, 0, 0, 0, 0};
  for (int d = t; d < EFFECT_DIM; d += 256) {
    p[0] += (double)W_emb[(size_t)id * EFFECT_DIM + d];
#pragma unroll
    for (int k = 0; k < NSYN; ++k)
      p[k + 1] += (double)W_emb[(size_t)sid[k] * EFFECT_DIM + d];
  }

  __shared__ double s_red[9][4];
  const int w = t >> 6;
#pragma unroll
  for (int k = 0; k < 9; ++k) {
    double v = p[k];
#pragma unroll
    for (int off = 32; off > 0; off >>= 1) v += __shfl_down(v, off, 64);
    if ((t & 63) == 0) s_red[k][w] = v;
  }
  __syncthreads();

  const double isum = s_red[0][0] + s_red[0][1] + s_red[0][2] + s_red[0][3];
  float coef[NSYN];
#pragma unroll
  for (int k = 0; k < NSYN; ++k) {
    double ss = s_red[k + 1][0] + s_red[k + 1][1] + s_red[k + 1][2] + s_red[k + 1][3];
    coef[k] = msk[k] ? (float)(isum / ss) : 0.0f;
  }

  const int r = l & 255;
  char* wbase = ws + (size_t)(l >> 8) * (12 * TILE_B);

  for (int j = t; j < 384; j += 256) {
    const int d0 = 2 * j;
    float v0, v1;
    if (d0 < EFFECT_DIM) {
      const float* bp = W_emb + (size_t)id * EFFECT_DIM + d0;
      v0 = bp[0];
      v1 = bp[1];
#pragma unroll
      for (int k = 0; k < NSYN; ++k) {
        const float* sp = W_emb + (size_t)sid[k] * EFFECT_DIM + d0;
        v0 = fmaf(coef[k], sp[0], v0);
        v1 = fmaf(coef[k], sp[1], v1);
      }
    } else {
      v0 = padding[l * ADD_DIM + (d0 - EFFECT_DIM)];
      v1 = padding[l * ADD_DIM + (d0 + 1 - EFFECT_DIM)];
    }
    const int ks = j >> 5;
    const int jl = j & 31;            // k-pair index within 64-k tile
    const int kap = jl >> 4;          // k-half unit
    const int off = (jl & 15) * 4;    // byte within 64B unit-row
    *(uint32_t*)(wbase + ks * TILE_B + kap * 16384 + r * 64 +
                 (off ^ ((r & 3) << 4))) = pack2(v0, v1);
  }
}

// ---------------------------------------------------------------------------
// Kernel 1b: W_rev f32 -> bf16 B tiles (372 n-tiles x 12 ks), k-half units.
// Block (j, ks) covers n [j*128, j*128+128) = half (j&1) of tile nt=j>>1.
// ---------------------------------------------------------------------------
__global__ __launch_bounds__(256) void conv_kernel(
    const float* __restrict__ Wrev, char* __restrict__ Bbuf)
{
  __shared__ char lds[16384];  // [k0-half 8K][k1-half 8K] for these 128 rows
  const int t   = threadIdx.x;
  const int j   = blockIdx.x;
  const int ks  = blockIdx.y;
  const int nl4 = t & 31;
  const int kc  = t >> 5;              // 0..7: 8-k group (16B)
  const int gn4 = j * 128 + nl4 * 4;
  const bool valid = (gn4 + 4) <= NCOLS;

  float4 v[8];
  const float* p = Wrev + (size_t)(ks * 64 + kc * 8) * NCOLS + gn4;
#pragma unroll
  for (int jj = 0; jj < 8; ++jj)
    v[jj] = valid ? *(const float4*)(p + (size_t)jj * NCOLS)
                  : float4{0.0f, 0.0f, 0.0f, 0.0f};

  const int kap = kc >> 2;
  const int sl  = (kc & 3) * 16;
#pragma unroll
  for (int i = 0; i < 4; ++i) {
    const int n = nl4 * 4 + i;   // local row 0..127 ((row&3) == (n&3))
    u32x4 u;
#pragma unroll
    for (int j2 = 0; j2 < 4; ++j2)
      u[j2] = pack2(F4C(v[2 * j2], i), F4C(v[2 * j2 + 1], i));
    *(u32x4*)(lds + kap * 8192 + n * 64 + (sl ^ ((n & 3) << 4))) = u;
  }
  __syncthreads();

  char* tile = Bbuf + (size_t)((j >> 1) * 12 + ks) * TILE_B;
#pragma unroll
  for (int i = 0; i < 4; ++i) {
    const int idx = i * 4096 + t * 16;
    const int kp  = idx >> 13;         // which k-half
    const int off = idx & 8191;
    *(u32x4*)(tile + kp * 16384 + (j & 1) * 8192 + off) =
        *(const u32x4*)(lds + idx);
  }
}

// ---------------------------------------------------------------------------
// Kernel 2: 256x256 tile, 512 threads, 8 waves (2m x 4n), wave-tile 128x64.
// 4-phase K-loop with k-half-unit staggered staging (T3), counted vmcnt(4)
// (T4: 2 units always in flight across barriers), setprio on MFMA (T5),
// T1 XCD remap (1488 = 8 x 186, bijective). LDS 128KB dynamic, 2 dbuf sets:
// set s: [A_k0 16K][A_k1 16K][B_k0 16K][B_k1 16K].
// Phase p of tile T: read kk=p frags (kappa=p>>1); stage one unit of T+1
// (order A_k0,B_k0,A_k1,B_k1); vmcnt+barrier at p=0,2 only.
// ---------------------------------------------------------------------------
__global__ __launch_bounds__(512, 2) void gemm_pre(
    const char* __restrict__ Abuf, const char* __restrict__ Bbuf,
    float* __restrict__ out)
{
  extern __shared__ char lds[];  // 131072
  const int t  = threadIdx.x;
  const int l  = t & 63;
  const int w  = t >> 6;   // 0..7
  const int wm = w >> 2;   // 0..1
  const int wn = w & 3;    // 0..3
  const int lr = l & 31;
  const int lh = l >> 5;

  const int wgid = blockIdx.x;            // 0..1487
  const int xcd  = wgid & 7;
  const int work = xcd * 186 + (wgid >> 3);
  const int mt = work & 3;
  const int nt = work >> 2;               // 0..371
  const int n0 = nt * 256;

  f32x16 acc[4][2] = {};

  const char* asrc = Abuf + (size_t)mt * (12 * TILE_B);
  const char* bsrc = Bbuf + (size_t)nt * (12 * TILE_B);

#define STAGEU(src, dst)                                                     \
  {                                                                          \
    GLOAD16((src) + w * 2048 + l * 16, (dst) + w * 2048);                    \
    GLOAD16((src) + w * 2048 + 1024 + l * 16, (dst) + w * 2048 + 1024);      \
  }

  // prologue: tile 0, order A_k0, B_k0, A_k1, B_k1
  STAGEU(asrc, lds + 0);
  STAGEU(bsrc, lds + 32768);
  STAGEU(asrc + 16384, lds + 16384);
  STAGEU(bsrc + 16384, lds + 49152);

  const int ra0 = wm * 128 + lr;   // + mr*32
  const int rb0 = wn * 64 + lr;    // + nr*32

  for (int T = 0; T < 12; ++T) {
    const char* sbase = lds + (T & 1) * 65536;
    char* dbase = lds + ((T & 1) ^ 1) * 65536;
    const char* atn = asrc + (T + 1) * TILE_B;
    const char* btn = bsrc + (T + 1) * TILE_B;
    const bool pf = (T < 11);

#pragma unroll
    for (int p = 0; p < 4; ++p) {
      if ((p & 1) == 0) {
        // wait for this kappa's 2 units; leave 2 units (4 loads) in flight
        if (pf || p == 0) asm volatile("s_waitcnt vmcnt(4)" ::: "memory");
        else              asm volatile("s_waitcnt vmcnt(0)" ::: "memory");
        __builtin_amdgcn_sched_barrier(0);
        __builtin_amdgcn_s_barrier();
      }
      const int kap  = p >> 1;
      const int koff = ((p & 1) << 5) | (lh << 4);

      // ds_read frags for kk=p
      bf16x8 a[4], b[2];
#pragma unroll
      for (int mr = 0; mr < 4; ++mr) {
        const int r = ra0 + mr * 32;
        a[mr] = *(const bf16x8*)(sbase + kap * 16384 + r * 64 +
                                 (koff ^ ((r & 3) << 4)));
      }
#pragma unroll
      for (int nr = 0; nr < 2; ++nr) {
        const int r = rb0 + nr * 32;
        b[nr] = *(const bf16x8*)(sbase + 32768 + kap * 16384 + r * 64 +
                                 (koff ^ ((r & 3) << 4)));
      }

      // stage one unit of tile T+1 into the other set
      if (pf) {
        if (p == 0)      STAGEU(atn,          dbase + 0)
        else if (p == 1) STAGEU(btn,          dbase + 32768)
        else if (p == 2) STAGEU(atn + 16384,  dbase + 16384)
        else             STAGEU(btn + 16384,  dbase + 49152)
      }

      asm volatile("s_waitcnt lgkmcnt(0)" ::: "memory");
      __builtin_amdgcn_sched_barrier(0);
      __builtin_amdgcn_s_setprio(1);
#pragma unroll
      for (int mr = 0; mr < 4; ++mr)
#pragma unroll
        for (int nr = 0; nr < 2; ++nr)
          acc[mr][nr] = __builtin_amdgcn_mfma_f32_32x32x16_bf16(
              a[mr], b[nr], acc[mr][nr], 0, 0, 0);
      __builtin_amdgcn_s_setprio(0);
    }
  }
#undef STAGEU

  // epilogue: C layout col=lane&31, row=(reg&3)+8*(reg>>2)+4*(lane>>5)
#pragma unroll
  for (int nr = 0; nr < 2; ++nr) {
    const int gc = n0 + wn * 64 + nr * 32 + lr;
    if (gc < NCOLS) {
#pragma unroll
      for (int mr = 0; mr < 4; ++mr)
#pragma unroll
        for (int reg = 0; reg < 16; ++reg) {
          const int row = (reg & 3) + 8 * (reg >> 2) + 4 * lh;
          const int gr = mt * 256 + wm * 128 + mr * 32 + row;
          out[(size_t)gr * NCOLS + gc] = acc[mr][nr][reg];
        }
    }
  }
}

// ---------------------------------------------------------------------------
// Fallback GEMM (ws too small for Bbuf): 128^2 tile, inline convert,
// adapted to the k-half-unit A layout. (Not taken on this harness.)
// ---------------------------------------------------------------------------
__global__ __launch_bounds__(256, 2) void gemm_kernel(
    const float* __restrict__ Wrev, const char* __restrict__ Abuf,
    float* __restrict__ out)
{
  __shared__ char lds[32768];  // A: [k0 8K][k1 8K]; B at 16384: [k0 8K][k1 8K]
  const int t  = threadIdx.x;
  const int l  = t & 63;
  const int w  = t >> 6;
  const int wm = w >> 1;
  const int wn = w & 1;
  const int lr = l & 31;
  const int lh = l >> 5;
  const int mt = blockIdx.x;
  const int n0 = blockIdx.y * 128;

  f32x16 acc[2][2] = {};

  const char* atile0 = Abuf + (size_t)(mt >> 1) * (12 * TILE_B);
  const int hoff = (mt & 1) * 8192;
  const int nl = t & 127;
  const int kc_base = t >> 7;
  const int gn = n0 + nl;

  for (int ks = 0; ks < 12; ++ks) {
    {
      const char* tile = atile0 + ks * TILE_B;
#pragma unroll
      for (int kap = 0; kap < 2; ++kap)
#pragma unroll
        for (int i = 0; i < 2; ++i)
          GLOAD16(tile + kap * 16384 + hoff + w * 2048 + i * 1024 + l * 16,
                  lds + kap * 8192 + w * 2048 + i * 1024);
    }
#pragma unroll
    for (int task = 0; task < 4; ++task) {
      const int kc = kc_base + task * 2;
      float v[8];
      const float* p = Wrev + (size_t)(ks * 64 + kc * 8) * NCOLS + gn;
#pragma unroll
      for (int j = 0; j < 8; ++j)
        v[j] = (gn < NCOLS) ? p[(size_t)j * NCOLS] : 0.0f;
      u32x4 u;
#pragma unroll
      for (int j = 0; j < 4; ++j)
        u[j] = pack2(v[2 * j], v[2 * j + 1]);
      *(u32x4*)(lds + 16384 + (kc >> 2) * 8192 + nl * 64 +
                (((kc & 3) * 16) ^ ((nl & 3) << 4))) = u;
    }
    __syncthreads();

#pragma unroll
    for (int kk = 0; kk < 4; ++kk) {
      const int kap  = kk >> 1;
      const int koff = ((kk & 1) << 5) | (lh << 4);
      bf16x8 a[2], b[2];
#pragma unroll
      for (int mr = 0; mr < 2; ++mr) {
        const int r = wm * 64 + mr * 32 + lr;
        a[mr] = *(const bf16x8*)(lds + kap * 8192 + r * 64 +
                                 (koff ^ ((r & 3) << 4)));
      }
#pragma unroll
      for (int nr = 0; nr < 2; ++nr) {
        const int r = wn * 64 + nr * 32 + lr;
        b[nr] = *(const bf16x8*)(lds + 16384 + kap * 8192 + r * 64 +
                                 (koff ^ ((r & 3) << 4)));
      }
#pragma unroll
      for (int mr = 0; mr < 2; ++mr)
#pragma unroll
        for (int nr = 0; nr < 2; ++nr)
          acc[mr][nr] = __builtin_amdgcn_mfma_f32_32x32x16_bf16(
              a[mr], b[nr], acc[mr][nr], 0, 0, 0);
    }
    __syncthreads();
  }

#pragma unroll
  for (int mr = 0; mr < 2; ++mr)
#pragma unroll
    for (int nr = 0; nr < 2; ++nr) {
      const int gc = n0 + wn * 64 + nr * 32 + lr;
      if (gc < NCOLS) {
#pragma unroll
        for (int reg = 0; reg < 16; ++reg) {
          const int row = (reg & 3) + 8 * (reg >> 2) + 4 * lh;
          const int gr = mt * 128 + wm * 64 + mr * 32 + row;
          out[(size_t)gr * NCOLS + gc] = acc[mr][nr][reg];
        }
      }
    }
}

extern "C" void kernel_launch(void* const* d_in, const int* in_sizes, int n_in,
                              void* d_out, int out_size, void* d_ws, size_t ws_size,
                              hipStream_t stream) {
  const int*   ids       = (const int*)d_in[0];
  const float* W_emb     = (const float*)d_in[1];
  const float* W_rev     = (const float*)d_in[2];
  const float* padding   = (const float*)d_in[3];
  const int*   syn_table = (const int*)d_in[4];
  const int*   syn_mask  = (const int*)d_in[5];
  float* out = (float*)d_out;
  char*  ws  = (char*)d_ws;

  const size_t A_BYTES = (size_t)4 * 12 * TILE_B;        // 1.5 MB
  const size_t B_BYTES = (size_t)NT256 * 12 * TILE_B;    // ~146 MB

  hipLaunchKernelGGL(emb_kernel, dim3(NROWS), dim3(256), 0, stream,
                     ids, W_emb, padding, syn_table, syn_mask, ws);

  if (ws_size >= A_BYTES + B_BYTES) {
    char* Bbuf = ws + A_BYTES;
    hipLaunchKernelGGL(conv_kernel, dim3(NT256 * 2, 12), dim3(256), 0, stream,
                       W_rev, Bbuf);
    // 1488 blocks exactly: 4 m-tiles x 372 n-tiles = 8 XCDs x 186
    hipLaunchKernelGGL(gemm_pre, dim3(4 * NT256), dim3(512), 131072, stream,
                       ws, Bbuf, out);
  } else {
    hipLaunchKernelGGL(gemm_kernel, dim3(8, (NCOLS + 127) / 128), dim3(256), 0,
                       stream, W_rev, ws, out);
  }
}